// Round 2
// baseline (152.618 us; speedup 1.0000x reference)
//
#include <hip/hip_runtime.h>
#include <math.h>

#define NBATCH 64
#define NGT    40
#define HW0    25600
#define HW1    6400
#define HW2    1600
#define SLICE  3200          // cells per block slice (sc0: 8 slices, sc1: 2, sc2: 1 of 1600)
#define BPB    11            // blocks per batch item: 8 + 2 + 1
#define NBLK   (NBATCH*BPB)  // 704
#define SENT   0xFFFFFFFFFFFFFFFFull
#define FEPS   1e-7f

__device__ __forceinline__ float sigm(float x){ return 1.0f/(1.0f+expf(-x)); }

// monotone float -> unsigned mapping (ascending float order == ascending uint order)
__device__ __forceinline__ unsigned fkey(float f){
  unsigned b = __float_as_uint(f);
  return (b & 0x80000000u) ? ~b : (b | 0x80000000u);
}

__device__ __forceinline__ unsigned long long shflx64(unsigned long long v, int m){
  int lo = __shfl_xor((int)(unsigned)(v & 0xFFFFFFFFull), m, 64);
  int hi = __shfl_xor((int)(unsigned)(v >> 32), m, 64);
  return (((unsigned long long)(unsigned)hi) << 32) | (unsigned)lo;
}
__device__ __forceinline__ float wredf(float v){
  #pragma unroll
  for (int o=32;o;o>>=1) v += __shfl_xor(v,o,64);
  return v;
}
__device__ __forceinline__ int wredi(int v){
  #pragma unroll
  for (int o=32;o;o>>=1) v += __shfl_xor(v,o,64);
  return v;
}
__device__ __forceinline__ unsigned long long wredmin64(unsigned long long v){
  #pragma unroll
  for (int o=32;o;o>>=1){ unsigned long long w = shflx64(v,o); v = (w<v)?w:v; }
  return v;
}

__device__ __forceinline__ float iou_of_cell(const float* __restrict__ P, int HW, int cell,
                                             int W, float s,
                                             float bx1, float by1, float bx2, float by2, float ab){
  int gy = cell / W;
  int gx = cell - gy*W;
  float gxf=(float)gx, gyf=(float)gy;
  float q1 = P[HW+cell], q2=P[2*HW+cell], q3=P[3*HW+cell], q4=P[4*HW+cell];
  float pcx = (sigm(q1)+gxf)*s;
  float pcy = (sigm(q2)+gyf)*s;
  float pw = expf(fminf(fmaxf(q3,-5.0f),5.0f))*s;
  float ph = expf(fminf(fmaxf(q4,-5.0f),5.0f))*s;
  float ax1=pcx-pw*0.5f, ay1=pcy-ph*0.5f, ax2=pcx+pw*0.5f, ay2=pcy+ph*0.5f;
  float ltx=fmaxf(ax1,bx1), lty=fmaxf(ay1,by1);
  float rbx=fminf(ax2,bx2), rby=fminf(ay2,by2);
  float iw=fmaxf(rbx-ltx,0.0f), ih=fmaxf(rby-lty,0.0f);
  float inter=iw*ih;
  float aa=(ax2-ax1)*(ay2-ay1);
  return inter/(aa+ab-inter+FEPS);
}

// One block per (b, slice). Assignment + loss fused; obj/winner live in LDS only.
__global__ __launch_bounds__(512) void k_fused(
    const float* __restrict__ p0, const float* __restrict__ p1,
    const float* __restrict__ p2, const float* __restrict__ tg,
    float* __restrict__ partials)
{
  __shared__ float s_obj[SLICE];
  __shared__ int   s_win[SLICE];
  __shared__ float red[4][8];

  int u = blockIdx.x;
  int b = u / BPB, r = u % BPB;
  int sc, off, cnt, W, HW; float s; const float* P;
  if (r < 8)       { sc=0; W=160; HW=HW0; s=8.0f/1280.0f;  off=r*SLICE;     cnt=SLICE; P=p0; }
  else if (r < 10) { sc=1; W=80;  HW=HW1; s=16.0f/1280.0f; off=(r-8)*SLICE; cnt=SLICE; P=p1; }
  else             { sc=2; W=40;  HW=HW2; s=32.0f/1280.0f; off=0;           cnt=HW2;   P=p2; }
  P += (size_t)b*7*HW;
  int ry0 = off / W, ry1 = (off + cnt) / W;   // slice row range [ry0, ry1)

  for (int j = threadIdx.x; j < cnt; j += 512){ s_obj[j]=0.0f; s_win[j]=-1; }
  __syncthreads();

  int wv = threadIdx.x >> 6, lane = threadIdx.x & 63;

  // ---- phase 2: per-wave GT tasks (full-rect scan, slice-filtered LDS scatter) ----
  for (int g = wv; g < NGT; g += 8){
    const float* tp = tg + (b*NGT + g)*7;
    float cls = tp[0], cx = tp[1], cy = tp[2], w = tp[3], h = tp[4];
    float sz = fmaxf(w,h)*1280.0f;
    bool valid = (cls == 0.0f);
    if (sc==0)      valid = valid && (sz < 128.0f);
    else if (sc==1) valid = valid && (sz >= 48.0f) && (sz < 288.0f);
    else            valid = valid && (sz >= 128.0f);
    if (!valid) continue;

    float cxg = cx/s, cyg = cy/s;
    float bx1 = cx - w*0.5f, bx2 = cx + w*0.5f;
    float by1 = cy - h*0.5f, by2 = cy + h*0.5f;
    float ab  = (bx2-bx1)*(by2-by1);
    float bxl = bx1/s, bxr = bx2/s, byt = by1/s, byb = by2/s;

    // bounding rect of (in_center | in_box), +1 margin; exact predicates inside
    int x0 = max(0,   (int)floorf(fminf(cxg-2.5f, bxl)) - 1);
    int x1 = min(W-1, (int)floorf(fmaxf(cxg+2.5f, bxr)) + 1);
    int y0 = max(0,   (int)floorf(fminf(cyg-2.5f, byt)) - 1);
    int y1 = min(W-1, (int)floorf(fmaxf(cyg+2.5f, byb)) + 1);
    if (y1 < ry0 || y0 >= ry1) continue;     // rect doesn't touch this slice
    int rw = x1-x0+1, rh = y1-y0+1;
    int rn = rw*rh;

    unsigned long long t[10];
    #pragma unroll
    for (int j=0;j<10;++j) t[j]=SENT;
    int ncand = 0; float iousum = 0.0f;
    unsigned long long dmin = SENT;

    int rx = lane % rw, ry = lane / rw;
    int stepy = 64 / rw, stepx = 64 % rw;
    for (int rr = lane; rr < rn; rr += 64){
      float gxf = (float)(x0+rx), gyf = (float)(y0+ry);
      int cell = (y0+ry)*W + (x0+rx);
      float q1 = P[HW+cell], q2 = P[2*HW+cell], q3 = P[3*HW+cell], q4 = P[4*HW+cell];
      float pcx = (sigm(q1)+gxf)*s;
      float pcy = (sigm(q2)+gyf)*s;
      float pw = expf(fminf(fmaxf(q3,-5.0f),5.0f))*s;
      float ph = expf(fminf(fmaxf(q4,-5.0f),5.0f))*s;
      float ax1 = pcx-pw*0.5f, ay1 = pcy-ph*0.5f, ax2 = pcx+pw*0.5f, ay2 = pcy+ph*0.5f;
      float ltx = fmaxf(ax1,bx1), lty = fmaxf(ay1,by1);
      float rbx = fminf(ax2,bx2), rby = fminf(ay2,by2);
      float iw = fmaxf(rbx-ltx,0.0f), ih = fmaxf(rby-lty,0.0f);
      float inter = iw*ih;
      float aa = (ax2-ax1)*(ay2-ay1);
      float iou = inter/(aa+ab-inter+FEPS);
      bool ic = (fabsf(gxf-cxg)<2.5f) && (fabsf(gyf-cyg)<2.5f);
      bool ib = (gxf>=bxl)&&(gxf<bxr)&&(gyf>=byt)&&(gyf<byb);
      float dx = gxf-cxg, dy = gyf-cyg;
      float dist = dx*dx+dy*dy;
      unsigned long long dk = (((unsigned long long)__float_as_uint(dist))<<32)|(unsigned)cell;
      dmin = (dk<dmin)?dk:dmin;
      if (ic|ib){
        ncand += 1; iousum += iou;
        float q0 = P[cell];
        float ccost = fmaxf(-q0,0.0f) + log1pf(expf(-fabsf(q0)));  // softplus(-q0)
        float cost = ccost - 3.0f*logf(iou+FEPS);
        unsigned long long pk = (((unsigned long long)fkey(cost))<<32)|(unsigned)cell;
        if (pk < t[9]){
          t[9] = pk;
          #pragma unroll
          for (int j=9;j>0;--j){ if (t[j]<t[j-1]){ unsigned long long tmp=t[j]; t[j]=t[j-1]; t[j-1]=tmp; } }
        }
      }
      rx += stepx; ry += stepy;
      if (rx >= rw){ rx -= rw; ry += 1; }
    }

    int NC = wredi(ncand);
    float IS = wredf(iousum);
    dmin = wredmin64(dmin);

    // 10 rounds of wave-wide min over per-lane sorted lists (keys unique per task)
    unsigned long long g10[10];
    int ptr = 0;
    #pragma unroll
    for (int rd=0; rd<10; ++rd){
      unsigned long long head = SENT;
      #pragma unroll
      for (int j=0;j<10;++j) head = (ptr==j)? t[j] : head;
      unsigned long long m = wredmin64(head);
      g10[rd] = m;
      if (head==m && m!=SENT) ptr += 1;
    }

    if (lane==0){
      unsigned cell0; int npos;
      if (NC==0){ cell0 = (unsigned)dmin; npos = 1; }   // fallback (never fires w/ this data)
      else {
        cell0 = (unsigned)g10[0];
        int ub = NC < 10 ? NC : 10;
        int v = (int)floorf(IS);
        v = v < 1 ? 1 : v;
        npos = v > ub ? ub : v;
      }
      float biou = iou_of_cell(P, HW, (int)cell0, W, s, bx1, by1, bx2, by2, ab);
      #pragma unroll
      for (int sl=0; sl<10; ++sl){
        if (sl < npos){
          int cell = (int)((sl==0)? cell0 : (unsigned)g10[sl]);
          if (cell >= off && cell < off+cnt){
            int l = cell - off;
            atomicMax(&s_win[l], g);                             // last-valid-GT-wins == max g
            atomicMax((int*)(s_obj+l), __float_as_int(biou));    // float max via int bits (>=0)
          }
        }
      }
    }
  }
  __syncthreads();

  // ---- phase 3: loss over this slice, obj/winner from LDS ----
  float osum=0.0f, np=0.0f, bsum=0.0f, fsum=0.0f;
  int i0 = off + threadIdx.x;
  int gy = i0 / W, gx = i0 - gy*W;
  int sy = 512 / W, sx = 512 - sy*W;
  for (int j = threadIdx.x; j < cnt; j += 512){
    int i = off + j;
    float x = P[i];
    float z = s_obj[j];
    float ce = fmaxf(x,0.0f) - x*z + log1pf(expf(-fabsf(x)));
    float prob = 1.0f/(1.0f+expf(-x));
    float p_t = prob*z + (1.0f-prob)*(1.0f-z);
    float a_t = 0.25f*z + 0.75f*(1.0f-z);
    float om = 1.0f - p_t;
    osum += a_t*om*om*ce;
    int wg = s_win[j];
    if (wg >= 0){
      np += 1.0f;
      const float* tp = tg + (b*NGT + wg)*7;
      float cx=tp[1], cy=tp[2], w=tp[3], h=tp[4], fx=tp[5], fy=tp[6];
      float gxf=(float)gx, gyf=(float)gy;
      float pcx = (sigm(P[HW+i])+gxf)*s;
      float pcy = (sigm(P[2*HW+i])+gyf)*s;
      float pw = expf(fminf(fmaxf(P[3*HW+i],-5.0f),5.0f))*s;
      float ph = expf(fminf(fmaxf(P[4*HW+i],-5.0f),5.0f))*s;
      float tw = w + FEPS*s, th = h + FEPS*s;   // exp(log(w/s+eps))*s
      float px1=pcx-pw*0.5f, py1=pcy-ph*0.5f, px2=pcx+pw*0.5f, py2=pcy+ph*0.5f;
      float tx1=cx-tw*0.5f, ty1=cy-th*0.5f, tx2=cx+tw*0.5f, ty2=cy+th*0.5f;
      float iw = fmaxf(fminf(px2,tx2)-fmaxf(px1,tx1),0.0f);
      float ih = fmaxf(fminf(py2,ty2)-fmaxf(py1,ty1),0.0f);
      float inter = iw*ih;
      float uni = pw*ph + tw*th - inter + FEPS;
      float iou = inter/uni;
      float rho2 = (pcx-cx)*(pcx-cx)+(pcy-cy)*(pcy-cy);
      float cw = fmaxf(px2,tx2)-fminf(px1,tx1);
      float ch = fmaxf(py2,ty2)-fminf(py1,ty1);
      float c2 = cw*cw+ch*ch+FEPS;
      float da = atanf(tw/(th+FEPS)) - atanf(pw/(ph+FEPS));
      float v = (4.0f/(float)(M_PI*M_PI))*da*da;
      float alpha = v/(1.0f-iou+v+FEPS);
      float ciou = iou - rho2/c2 - alpha*v;
      bsum += 1.0f - ciou;
      float pf1 = sigm(P[5*HW+i]), pf2 = sigm(P[6*HW+i]);
      float d1 = fabsf(pf1-fx), d2 = fabsf(pf2-fy);
      fsum += (d1<1.0f? 0.5f*d1*d1 : d1-0.5f) + (d2<1.0f? 0.5f*d2*d2 : d2-0.5f);
    }
    gx += sx; gy += sy;
    if (gx >= W){ gx -= W; gy += 1; }
  }
  osum = wredf(osum); np = wredf(np); bsum = wredf(bsum); fsum = wredf(fsum);
  if (lane==0){ red[0][wv]=osum; red[1][wv]=np; red[2][wv]=bsum; red[3][wv]=fsum; }
  __syncthreads();
  if (threadIdx.x==0){
    float a0=0,a1=0,a2=0,a3=0;
    #pragma unroll
    for (int j=0;j<8;++j){ a0+=red[0][j]; a1+=red[1][j]; a2+=red[2][j]; a3+=red[3][j]; }
    partials[u*4+0]=a0; partials[u*4+1]=a1; partials[u*4+2]=a2; partials[u*4+3]=a3;
  }
}

__global__ void k_final(const float* __restrict__ partials, float* __restrict__ out){
  int t = threadIdx.x;
  float c = 0.0f;
  if (t < 192){
    int b = t/3, sc = t%3;
    float os=0,np=0,bs=0,fs=0;
    int base = b*BPB;
    int r0, r1;
    if (sc==0){ r0=0; r1=8; }
    else if (sc==1){ r0=8; r1=10; }
    else { r0=10; r1=11; }
    for (int j=r0;j<r1;++j){
      const float* q = partials + (base+j)*4;
      os+=q[0]; np+=q[1]; bs+=q[2]; fs+=q[3];
    }
    float hw = (sc==0)?25600.0f:(sc==1)?6400.0f:1600.0f;
    float npos = fmaxf(np, 1.0f);
    c = os/hw + 5.0f*bs/npos + fs/npos;
  }
  __shared__ float sh[256];
  sh[t] = c;
  __syncthreads();
  for (int s2=128; s2>0; s2>>=1){
    if (t < s2) sh[t] += sh[t+s2];
    __syncthreads();
  }
  if (t==0) out[0] = sh[0]*(1.0f/64.0f);
}

extern "C" void kernel_launch(void* const* d_in, const int* in_sizes, int n_in,
                              void* d_out, int out_size, void* d_ws, size_t ws_size,
                              hipStream_t stream) {
  (void)in_sizes; (void)n_in; (void)out_size; (void)ws_size;
  const float* p0 = (const float*)d_in[0];
  const float* p1 = (const float*)d_in[1];
  const float* p2 = (const float*)d_in[2];
  const float* tg = (const float*)d_in[3];

  float* partials = (float*)d_ws;          // NBLK*4 floats
  float* out      = (float*)d_out;

  k_fused<<<NBLK, 512, 0, stream>>>(p0, p1, p2, tg, partials);
  k_final<<<1, 256, 0, stream>>>(partials, out);
}

// Round 3
// 128.332 us; speedup vs baseline: 1.1892x; 1.1892x over previous
//
#include <hip/hip_runtime.h>
#include <math.h>

#define NBATCH 64
#define NGT    40
#define HW0    25600
#define HW1    6400
#define HW2    1600
#define NTASK  (NBATCH*3*NGT)   // 7680
#define SLICE  1600
#define BPB    21               // slices per batch item: 16 + 4 + 1
#define NBLK   (NBATCH*BPB)     // 1344
#define SENT   0xFFFFFFFFFFFFFFFFull
#define FEPS   1e-7f

__device__ __forceinline__ float sigm(float x){ return 1.0f/(1.0f+expf(-x)); }

// monotone float -> unsigned mapping (ascending float order == ascending uint order)
__device__ __forceinline__ unsigned fkey(float f){
  unsigned b = __float_as_uint(f);
  return (b & 0x80000000u) ? ~b : (b | 0x80000000u);
}

__device__ __forceinline__ unsigned long long shflx64(unsigned long long v, int m){
  int lo = __shfl_xor((int)(unsigned)(v & 0xFFFFFFFFull), m, 64);
  int hi = __shfl_xor((int)(unsigned)(v >> 32), m, 64);
  return (((unsigned long long)(unsigned)hi) << 32) | (unsigned)lo;
}
__device__ __forceinline__ float wredf(float v){
  #pragma unroll
  for (int o=32;o;o>>=1) v += __shfl_xor(v,o,64);
  return v;
}
__device__ __forceinline__ int wredi(int v){
  #pragma unroll
  for (int o=32;o;o>>=1) v += __shfl_xor(v,o,64);
  return v;
}
__device__ __forceinline__ unsigned long long wredmin64(unsigned long long v){
  #pragma unroll
  for (int o=32;o;o>>=1){ unsigned long long w = shflx64(v,o); v = (w<v)?w:v; }
  return v;
}

__device__ __forceinline__ float iou_of_cell(const float* __restrict__ P, int HW, int cell,
                                             int W, float s,
                                             float bx1, float by1, float bx2, float by2, float ab){
  int gy = cell / W;
  int gx = cell - gy*W;
  float gxf=(float)gx, gyf=(float)gy;
  float q1 = P[HW+cell], q2=P[2*HW+cell], q3=P[3*HW+cell], q4=P[4*HW+cell];
  float pcx = (sigm(q1)+gxf)*s;
  float pcy = (sigm(q2)+gyf)*s;
  float pw = expf(fminf(fmaxf(q3,-5.0f),5.0f))*s;
  float ph = expf(fminf(fmaxf(q4,-5.0f),5.0f))*s;
  float ax1=pcx-pw*0.5f, ay1=pcy-ph*0.5f, ax2=pcx+pw*0.5f, ay2=pcy+ph*0.5f;
  float ltx=fmaxf(ax1,bx1), lty=fmaxf(ay1,by1);
  float rbx=fminf(ax2,bx2), rby=fminf(ay2,by2);
  float iw=fmaxf(rbx-ltx,0.0f), ih=fmaxf(rby-lty,0.0f);
  float inter=iw*ih;
  float aa=(ax2-ax1)*(ay2-ay1);
  return inter/(aa+ab-inter+FEPS);
}

// one wave per (b, sc, g) task -> compact output (npos, biou, <=10 cells)
__global__ __launch_bounds__(256) void k_assign(
    const float* __restrict__ p0, const float* __restrict__ p1,
    const float* __restrict__ p2, const float* __restrict__ tg,
    int2* __restrict__ meta, int* __restrict__ cells)
{
  int lane = threadIdx.x & 63;
  int task = ((blockIdx.x<<8) + threadIdx.x) >> 6;   // 0..7679
  int g  = task % NGT;
  int bs = task / NGT;
  int sc = bs % 3;
  int b  = bs / 3;

  const float* tp = tg + (b*NGT + g)*7;
  float cls = tp[0], cx = tp[1], cy = tp[2], w = tp[3], h = tp[4];
  float sz = fmaxf(w,h)*1280.0f;
  bool valid = (cls == 0.0f);
  if (sc==0)      valid = valid && (sz < 128.0f);
  else if (sc==1) valid = valid && (sz >= 48.0f) && (sz < 288.0f);
  else            valid = valid && (sz >= 128.0f);
  if (!valid){ if (lane==0) meta[task] = make_int2(0,0); return; }

  int W, HW; float s; const float* P;
  if (sc==0)      { W=160; HW=HW0; s=8.0f/1280.0f;  P=p0; }
  else if (sc==1) { W=80;  HW=HW1; s=16.0f/1280.0f; P=p1; }
  else            { W=40;  HW=HW2; s=32.0f/1280.0f; P=p2; }
  P += (size_t)b*7*HW;

  float cxg = cx/s, cyg = cy/s;
  float bx1 = cx - w*0.5f, bx2 = cx + w*0.5f;
  float by1 = cy - h*0.5f, by2 = cy + h*0.5f;
  float ab  = (bx2-bx1)*(by2-by1);
  float bxl = bx1/s, bxr = bx2/s, byt = by1/s, byb = by2/s;

  // bounding rect of (in_center | in_box), +1 margin; exact predicates inside
  int x0 = max(0,   (int)floorf(fminf(cxg-2.5f, bxl)) - 1);
  int x1 = min(W-1, (int)floorf(fmaxf(cxg+2.5f, bxr)) + 1);
  int y0 = max(0,   (int)floorf(fminf(cyg-2.5f, byt)) - 1);
  int y1 = min(W-1, (int)floorf(fmaxf(cyg+2.5f, byb)) + 1);
  int rw = x1-x0+1, rh = y1-y0+1;
  int rn = rw*rh;

  unsigned long long t[10];
  #pragma unroll
  for (int j=0;j<10;++j) t[j]=SENT;
  int ncand = 0; float iousum = 0.0f;
  unsigned long long dmin = SENT;

  int rx = lane % rw, ry = lane / rw;
  int stepy = 64 / rw, stepx = 64 % rw;
  for (int r = lane; r < rn; r += 64){
    float gxf = (float)(x0+rx), gyf = (float)(y0+ry);
    int cell = (y0+ry)*W + (x0+rx);
    float q1 = P[HW+cell], q2 = P[2*HW+cell], q3 = P[3*HW+cell], q4 = P[4*HW+cell];
    float pcx = (sigm(q1)+gxf)*s;
    float pcy = (sigm(q2)+gyf)*s;
    float pw = expf(fminf(fmaxf(q3,-5.0f),5.0f))*s;
    float ph = expf(fminf(fmaxf(q4,-5.0f),5.0f))*s;
    float ax1 = pcx-pw*0.5f, ay1 = pcy-ph*0.5f, ax2 = pcx+pw*0.5f, ay2 = pcy+ph*0.5f;
    float ltx = fmaxf(ax1,bx1), lty = fmaxf(ay1,by1);
    float rbx = fminf(ax2,bx2), rby = fminf(ay2,by2);
    float iw = fmaxf(rbx-ltx,0.0f), ih = fmaxf(rby-lty,0.0f);
    float inter = iw*ih;
    float aa = (ax2-ax1)*(ay2-ay1);
    float iou = inter/(aa+ab-inter+FEPS);
    bool ic = (fabsf(gxf-cxg)<2.5f) && (fabsf(gyf-cyg)<2.5f);
    bool ib = (gxf>=bxl)&&(gxf<bxr)&&(gyf>=byt)&&(gyf<byb);
    float dx = gxf-cxg, dy = gyf-cyg;
    float dist = dx*dx+dy*dy;
    unsigned long long dk = (((unsigned long long)__float_as_uint(dist))<<32)|(unsigned)cell;
    dmin = (dk<dmin)?dk:dmin;
    if (ic|ib){
      ncand += 1; iousum += iou;
      float q0 = P[cell];
      float ccost = fmaxf(-q0,0.0f) + log1pf(expf(-fabsf(q0)));  // softplus(-q0)
      float cost = ccost - 3.0f*logf(iou+FEPS);
      unsigned long long pk = (((unsigned long long)fkey(cost))<<32)|(unsigned)cell;
      if (pk < t[9]){
        t[9] = pk;
        #pragma unroll
        for (int j=9;j>0;--j){ if (t[j]<t[j-1]){ unsigned long long tmp=t[j]; t[j]=t[j-1]; t[j-1]=tmp; } }
      }
    }
    rx += stepx; ry += stepy;
    if (rx >= rw){ rx -= rw; ry += 1; }
  }

  int NC = wredi(ncand);
  float IS = wredf(iousum);
  dmin = wredmin64(dmin);

  // 10 rounds of wave-wide min over per-lane sorted lists (keys unique per task)
  unsigned long long g10[10];
  int ptr = 0;
  #pragma unroll
  for (int rd=0; rd<10; ++rd){
    unsigned long long head = SENT;
    #pragma unroll
    for (int j=0;j<10;++j) head = (ptr==j)? t[j] : head;
    unsigned long long m = wredmin64(head);
    g10[rd] = m;
    if (head==m && m!=SENT) ptr += 1;
  }

  if (lane==0){
    unsigned cell0; int npos;
    if (NC==0){ cell0 = (unsigned)dmin; npos = 1; }   // fallback (never fires w/ this data)
    else {
      cell0 = (unsigned)g10[0];
      int ub = NC < 10 ? NC : 10;
      int v = (int)floorf(IS);
      v = v < 1 ? 1 : v;
      npos = v > ub ? ub : v;
    }
    float biou = iou_of_cell(P, HW, (int)cell0, W, s, bx1, by1, bx2, by2, ab);
    meta[task] = make_int2(npos, __float_as_int(biou));
    #pragma unroll
    for (int sl=0; sl<10; ++sl){
      if (sl < npos) cells[task*10 + sl] = (int)((sl==0)? cell0 : (unsigned)g10[sl]);
    }
  }
}

// per-slice loss; obj/winner rebuilt in LDS from compact task entries
template<int W, int HW>
__device__ __forceinline__ void loss_slice(
    const float* __restrict__ P, const float* __restrict__ tg,
    int b, int off, float s,
    const float* __restrict__ s_obj, const int* __restrict__ s_win, float* acc)
{
  int tid = threadIdx.x;
  int i0 = off + tid;
  int gy = i0 / W;           // compile-time W
  int gx = i0 - gy*W;
  const int SY = 320 / W;    // 2, 4, 8 (320 divisible by all W)
  float xv[5];
  #pragma unroll
  for (int k=0;k<5;++k) xv[k] = P[i0 + k*320];
  #pragma unroll
  for (int k=0;k<5;++k){
    int j = tid + k*320;
    int i = off + j;
    float x = xv[k];
    float z = s_obj[j];
    float e = __expf(-fabsf(x));
    float ce = fmaxf(x,0.0f) - x*z + __logf(1.0f + e);
    float prob = 1.0f/(1.0f + __expf(-x));
    float p_t = prob*z + (1.0f-prob)*(1.0f-z);
    float a_t = 0.25f*z + 0.75f*(1.0f-z);
    float om = 1.0f - p_t;
    acc[0] += a_t*om*om*ce;
    int wg = s_win[j];
    if (wg >= 0){
      acc[1] += 1.0f;
      const float* tp = tg + (b*NGT + wg)*7;
      float cx=tp[1], cy=tp[2], w=tp[3], h=tp[4], fx=tp[5], fy=tp[6];
      float gxf=(float)gx, gyf=(float)gy;
      float pcx = (1.0f/(1.0f+__expf(-P[HW+i]))+gxf)*s;
      float pcy = (1.0f/(1.0f+__expf(-P[2*HW+i]))+gyf)*s;
      float pw = __expf(fminf(fmaxf(P[3*HW+i],-5.0f),5.0f))*s;
      float ph = __expf(fminf(fmaxf(P[4*HW+i],-5.0f),5.0f))*s;
      float tw = w + FEPS*s, th = h + FEPS*s;   // exp(log(w/s+eps))*s
      float px1=pcx-pw*0.5f, py1=pcy-ph*0.5f, px2=pcx+pw*0.5f, py2=pcy+ph*0.5f;
      float tx1=cx-tw*0.5f, ty1=cy-th*0.5f, tx2=cx+tw*0.5f, ty2=cy+th*0.5f;
      float iw = fmaxf(fminf(px2,tx2)-fmaxf(px1,tx1),0.0f);
      float ih = fmaxf(fminf(py2,ty2)-fmaxf(py1,ty1),0.0f);
      float inter = iw*ih;
      float uni = pw*ph + tw*th - inter + FEPS;
      float iou = inter/uni;
      float rho2 = (pcx-cx)*(pcx-cx)+(pcy-cy)*(pcy-cy);
      float cw = fmaxf(px2,tx2)-fminf(px1,tx1);
      float ch = fmaxf(py2,ty2)-fminf(py1,ty1);
      float c2 = cw*cw+ch*ch+FEPS;
      float da = atanf(tw/(th+FEPS)) - atanf(pw/(ph+FEPS));
      float v = (4.0f/(float)(M_PI*M_PI))*da*da;
      float alpha = v/(1.0f-iou+v+FEPS);
      float ciou = iou - rho2/c2 - alpha*v;
      acc[2] += 1.0f - ciou;
      float pf1 = 1.0f/(1.0f+__expf(-P[5*HW+i]));
      float pf2 = 1.0f/(1.0f+__expf(-P[6*HW+i]));
      float d1 = fabsf(pf1-fx), d2 = fabsf(pf2-fy);
      acc[3] += (d1<1.0f? 0.5f*d1*d1 : d1-0.5f) + (d2<1.0f? 0.5f*d2*d2 : d2-0.5f);
    }
    gy += SY;
  }
}

__global__ __launch_bounds__(320) void k_loss(
    const float* __restrict__ p0, const float* __restrict__ p1,
    const float* __restrict__ p2, const float* __restrict__ tg,
    const int2* __restrict__ meta, const int* __restrict__ cells,
    float* __restrict__ partials)
{
  __shared__ float s_obj[SLICE];
  __shared__ int   s_win[SLICE];
  __shared__ float red[4][5];

  int u = blockIdx.x;
  int b = u / BPB, r = u % BPB;
  int sc, off, HW; const float* P; float s;
  if (r < 16)      { sc=0; HW=HW0; s=8.0f/1280.0f;  off=r*SLICE;      P=p0; }
  else if (r < 20) { sc=1; HW=HW1; s=16.0f/1280.0f; off=(r-16)*SLICE; P=p1; }
  else             { sc=2; HW=HW2; s=32.0f/1280.0f; off=0;            P=p2; }
  P += (size_t)b*7*HW;

  for (int j = threadIdx.x; j < SLICE; j += 320){ s_obj[j]=0.0f; s_win[j]=-1; }
  __syncthreads();

  int tbase = (b*3 + sc)*NGT;
  for (int t = threadIdx.x; t < NGT*10; t += 320){
    int g = t / 10, sl = t % 10;
    int2 m = meta[tbase + g];
    if (sl < m.x){
      int l = cells[(tbase+g)*10 + sl] - off;
      if (l >= 0 && l < SLICE){
        atomicMax(&s_win[l], g);
        atomicMax((int*)(s_obj+l), m.y);   // biou >= 0: float max via int bits
      }
    }
  }
  __syncthreads();

  float acc[4] = {0.0f,0.0f,0.0f,0.0f};
  if (sc==0)      loss_slice<160,HW0>(P, tg, b, off, s, s_obj, s_win, acc);
  else if (sc==1) loss_slice<80, HW1>(P, tg, b, off, s, s_obj, s_win, acc);
  else            loss_slice<40, HW2>(P, tg, b, off, s, s_obj, s_win, acc);

  int wv = threadIdx.x >> 6, lane = threadIdx.x & 63;
  #pragma unroll
  for (int q=0;q<4;++q) acc[q] = wredf(acc[q]);
  if (lane==0){ red[0][wv]=acc[0]; red[1][wv]=acc[1]; red[2][wv]=acc[2]; red[3][wv]=acc[3]; }
  __syncthreads();
  if (threadIdx.x==0){
    float a0=0,a1=0,a2=0,a3=0;
    #pragma unroll
    for (int j=0;j<5;++j){ a0+=red[0][j]; a1+=red[1][j]; a2+=red[2][j]; a3+=red[3][j]; }
    partials[u*4+0]=a0; partials[u*4+1]=a1; partials[u*4+2]=a2; partials[u*4+3]=a3;
  }
}

__global__ void k_final(const float* __restrict__ partials, float* __restrict__ out){
  int t = threadIdx.x;
  float c = 0.0f;
  if (t < 192){
    int b = t/3, sc = t%3;
    float os=0,np=0,bs=0,fs=0;
    int base = b*BPB;
    int r0, r1;
    if (sc==0){ r0=0; r1=16; }
    else if (sc==1){ r0=16; r1=20; }
    else { r0=20; r1=21; }
    for (int j=r0;j<r1;++j){
      const float* q = partials + (base+j)*4;
      os+=q[0]; np+=q[1]; bs+=q[2]; fs+=q[3];
    }
    float hw = (sc==0)?25600.0f:(sc==1)?6400.0f:1600.0f;
    float npos = fmaxf(np, 1.0f);
    c = os/hw + 5.0f*bs/npos + fs/npos;
  }
  __shared__ float sh[256];
  sh[t] = c;
  __syncthreads();
  for (int s2=128; s2>0; s2>>=1){
    if (t < s2) sh[t] += sh[t+s2];
    __syncthreads();
  }
  if (t==0) out[0] = sh[0]*(1.0f/64.0f);
}

extern "C" void kernel_launch(void* const* d_in, const int* in_sizes, int n_in,
                              void* d_out, int out_size, void* d_ws, size_t ws_size,
                              hipStream_t stream) {
  (void)in_sizes; (void)n_in; (void)out_size; (void)ws_size;
  const float* p0 = (const float*)d_in[0];
  const float* p1 = (const float*)d_in[1];
  const float* p2 = (const float*)d_in[2];
  const float* tg = (const float*)d_in[3];

  int2*  meta     = (int2*)d_ws;                                      // NTASK int2
  int*   cells    = (int*)((char*)d_ws + (size_t)NTASK*8);            // NTASK*10 int
  float* partials = (float*)((char*)d_ws + (size_t)NTASK*8 + (size_t)NTASK*40);  // NBLK*4
  float* out      = (float*)d_out;

  k_assign<<<NTASK/4, 256, 0, stream>>>(p0, p1, p2, tg, meta, cells);
  k_loss  <<<NBLK, 320, 0, stream>>>(p0, p1, p2, tg, meta, cells, partials);
  k_final <<<1, 256, 0, stream>>>(partials, out);
}